// Round 3
// baseline (115.808 us; speedup 1.0000x reference)
//
#include <hip/hip_runtime.h>
#include <hip/hip_bf16.h>
#include <cstdint>

// Problem dims (fixed by the reference):
//   x: [8, 8192, 512] f32 -> LN over E=512 -> view as A=[16384, 2048]
//   (reshape is row-major flatten: A[m][k] = LN(x_flat)[m*2048+k])
//   W: [2048, 512] f32, b: [512];  out: [16384, 512] f32 = gelu(A @ W' + b')
//   where W' = gamma-folded W, b' = b + beta @ W  (LN affine folded out)
#define XROWS   65536
#define E       512
#define MROWS   16384
#define KDIM    2048
#define NDIM    512
#define NT      32        // K-steps of 64

typedef __attribute__((ext_vector_type(4))) float f32x4;
typedef __attribute__((ext_vector_type(2))) float f32x2;
typedef __attribute__((ext_vector_type(8))) unsigned short u16x8;
typedef __attribute__((ext_vector_type(8))) __bf16 bf16x8;

__device__ __forceinline__ unsigned short f2bf(float f) {
  unsigned u = __builtin_bit_cast(unsigned, f);
  u += 0x7FFFu + ((u >> 16) & 1u);   // round-to-nearest-even
  return (unsigned short)(u >> 16);
}

// async global->LDS, 16B per lane; LDS dest is wave-uniform base + lane*16
typedef const __attribute__((address_space(1))) unsigned char ga_u8;
typedef __attribute__((address_space(3))) unsigned char ls_u8;
__device__ __forceinline__ void gload16(const void* g, void* l) {
  __builtin_amdgcn_global_load_lds((ga_u8*)g, (ls_u8*)l, 16, 0, 0);
}

// fast exact-enough gelu: tanh form via native exp2/rcp.
// gelu ~= v*E/(E+1), E = 2^(v*(c1 + c3*v^2));  |err vs erf-form| <= ~3e-3
__device__ __forceinline__ float gelu_f(float v) {
  float p = v * (2.3022083f + 0.1029432f * (v * v));
  p = fminf(p, 80.0f);                       // overflow guard (E=inf -> NaN)
  const float Ee = exp2f(p);                 // native v_exp_f32
  return v * Ee * __builtin_amdgcn_rcpf(Ee + 1.0f);
}

// ---------------------------------------------------------------------------
// W [2048][512] f32 -> WT [512][2048] bf16 with gamma folded in:
//   WT[n][k] = bf16(gamma[k % 512] * W[k][n])
// grid: 256 blocks (32 k-tiles x 8 n-tiles), 256 threads
// ---------------------------------------------------------------------------
__global__ __launch_bounds__(256) void wt_kernel(const float* __restrict__ W,
                                                 const float* __restrict__ gamma,
                                                 unsigned short* __restrict__ WT) {
  __shared__ float tile[64][68];
  const int t  = threadIdx.x;
  const int bk = blockIdx.x >> 3;
  const int bn = blockIdx.x & 7;
  const int c4 = (t & 15) * 4;
#pragma unroll
  for (int i = 0; i < 4; ++i) {
    const int r = (t >> 4) + i * 16;
    const f32x4 v = *(const f32x4*)&W[(size_t)(bk * 64 + r) * NDIM + bn * 64 + c4];
    tile[r][c4 + 0] = v.x; tile[r][c4 + 1] = v.y;
    tile[r][c4 + 2] = v.z; tile[r][c4 + 3] = v.w;
  }
  __syncthreads();
#pragma unroll
  for (int j = 0; j < 2; ++j) {
    const int n  = j * 32 + (t >> 3);
    const int kb = (t & 7) * 8;
    const int kg0 = (bk & 7) * 64 + kb;      // gamma idx = global k & 511
    const f32x4 g0 = *(const f32x4*)(gamma + kg0);
    const f32x4 g1 = *(const f32x4*)(gamma + kg0 + 4);
    const float gg[8] = {g0.x, g0.y, g0.z, g0.w, g1.x, g1.y, g1.z, g1.w};
    u16x8 o;
#pragma unroll
    for (int q = 0; q < 8; ++q) o[q] = f2bf(gg[q] * tile[kb + q][n]);
    *(u16x8*)&WT[(size_t)(bn * 64 + n) * KDIM + bk * 64 + kb] = o;
  }
}

// ---------------------------------------------------------------------------
// beta fold, deterministic 2-stage: partial[32][512] then reduce + b.
// ---------------------------------------------------------------------------
__global__ __launch_bounds__(256) void kbias1(const float* __restrict__ W,
                                              const float* __restrict__ beta,
                                              float* __restrict__ partial) {
  const int bk = blockIdx.x, tid = threadIdx.x;
  float a0 = 0.f, a1 = 0.f;
  for (int k = 0; k < 64; ++k) {
    const int kg = bk * 64 + k;
    const float be = beta[kg & (E - 1)];
    a0 += be * W[(size_t)kg * NDIM + tid];
    a1 += be * W[(size_t)kg * NDIM + 256 + tid];
  }
  partial[bk * NDIM + tid] = a0;
  partial[bk * NDIM + 256 + tid] = a1;
}

__global__ __launch_bounds__(256) void kbias2(const float* __restrict__ b,
                                              const float* __restrict__ partial,
                                              float* __restrict__ biasf) {
  const int c = blockIdx.x * 256 + threadIdx.x;   // grid 2 x 256
  float s = b[c];
  for (int j = 0; j < 32; ++j) s += partial[j * NDIM + c];
  biasf[c] = s;
}

// ---------------------------------------------------------------------------
// Stats: one wave per x-row of 512 -> (rs, nm) = (rstd, -mean*rstd)
// ---------------------------------------------------------------------------
__global__ __launch_bounds__(256, 4) void stats_kernel(const float* __restrict__ x,
                                                       f32x2* __restrict__ stats) {
  const int w = threadIdx.x >> 6, l = threadIdx.x & 63;
  const size_t row = (size_t)blockIdx.x * 4 + w;
  const float* xr = x + row * E + l * 8;
  const f32x4 v0 = *(const f32x4*)xr;
  const f32x4 v1 = *(const f32x4*)(xr + 4);
  float s = v0.x + v0.y + v0.z + v0.w + v1.x + v1.y + v1.z + v1.w;
  float q = v0.x * v0.x + v0.y * v0.y + v0.z * v0.z + v0.w * v0.w
          + v1.x * v1.x + v1.y * v1.y + v1.z * v1.z + v1.w * v1.w;
#pragma unroll
  for (int off = 32; off > 0; off >>= 1) {
    s += __shfl_xor(s, off);
    q += __shfl_xor(q, off);
  }
  if (l == 0) {
    const float mean = s * (1.0f / E);
    const float var  = q * (1.0f / E) - mean * mean;
    const float rs   = rsqrtf(var + 1e-6f);
    f32x2 o; o.x = rs; o.y = -mean * rs;
    stats[row] = o;
  }
}

// ---------------------------------------------------------------------------
// Fused norm+GEMM: A from x f32 (reg-staged, LN fma, bf16 pack, swizzled
// ds_write), B from WT via gload_lds (pre-swizzled source, linear dest).
// Tile 64x256, 4 waves of 64x64, BK=64, dbuf LDS = 2*(8K A + 32K B) = 80 KB
// -> 2 blocks/CU. grid = 256 M-panels x 2 N-panels = 512.
// 2-step-deep A-reg pipeline: load x(t+2) | convert+write(t+1) | mfma(t).
// ---------------------------------------------------------------------------
__global__ __launch_bounds__(256, 2) void gemm_kernel(const float* __restrict__ x,
                                                      const f32x2* __restrict__ stats,
                                                      const unsigned short* __restrict__ Bt,
                                                      const float* __restrict__ biasf,
                                                      float* __restrict__ out) {
  __shared__ char smem[2 * 40960];   // per buf: A 8KB @0, B 32KB @8192
  const int tid = threadIdx.x;
  const int l = tid & 63, w = tid >> 6;
  const int l7 = l & 7, l15 = l & 15, lhi = l >> 4;

  const int bn = blockIdx.x & 1;
  const int bm = blockIdx.x >> 1;
  const size_t mrow0 = (size_t)bm * 64;
  const int    ncol0 = bn * 256;

  // A staging: round r in {0,1}: A-row = tid/8 + r*32, f32 cols (tid&7)*8..+8
  const int amrow = tid >> 3;
  const int acol  = (tid & 7) * 8;
  const float* gx = x + (mrow0 + amrow) * KDIM + acol;   // A[m][k]=x_flat[m*2048+k]
  const int sbase = (int)(mrow0 + amrow) * 4;            // stats idx + tok
  const int awz   = ((tid & 7) * 16) ^ ((amrow & 7) << 4);

  // B staging: gload16 x8, rows i*32 + w*8 + l/8, pre-swizzled source col
  const int bsrow = w * 8 + (l >> 3);
  const int bswz  = (l7 * 16) ^ ((l >> 3) << 4);
  const char* gB = (const char*)Bt + ((size_t)(ncol0 + bsrow) * KDIM) * 2 + bswz;

  f32x4 acc[4][4];
#pragma unroll
  for (int m = 0; m < 4; ++m)
#pragma unroll
    for (int n = 0; n < 4; ++n) acc[m][n] = (f32x4){0.f, 0.f, 0.f, 0.f};

  const int cs0 = (lhi * 16) ^ (l7 * 16);

  f32x4 xa0[4], xa1[4];
  f32x2 st0[2], st1[2];

  auto loadx = [&](f32x4* XA, f32x2* ST, int t) {
    const float* p = gx + (size_t)t * 64;
    XA[0] = *(const f32x4*)(p);
    XA[1] = *(const f32x4*)(p + 4);
    XA[2] = *(const f32x4*)(p + (size_t)32 * KDIM);
    XA[3] = *(const f32x4*)(p + (size_t)32 * KDIM + 4);
    ST[0] = stats[sbase + (t >> 3)];
    ST[1] = stats[sbase + 128 + (t >> 3)];
  };
  auto writeA = [&](const f32x4* XA, const f32x2* ST, int t) {
    char* ab = smem + (t & 1) * 40960;
    u16x8 o;
    float rs = ST[0].x, nm = ST[0].y;
    o[0] = f2bf(XA[0].x * rs + nm); o[1] = f2bf(XA[0].y * rs + nm);
    o[2] = f2bf(XA[0].z * rs + nm); o[3] = f2bf(XA[0].w * rs + nm);
    o[4] = f2bf(XA[1].x * rs + nm); o[5] = f2bf(XA[1].y * rs + nm);
    o[6] = f2bf(XA[1].z * rs + nm); o[7] = f2bf(XA[1].w * rs + nm);
    *(u16x8*)(ab + amrow * 128 + awz) = o;
    rs = ST[1].x; nm = ST[1].y;
    o[0] = f2bf(XA[2].x * rs + nm); o[1] = f2bf(XA[2].y * rs + nm);
    o[2] = f2bf(XA[2].z * rs + nm); o[3] = f2bf(XA[2].w * rs + nm);
    o[4] = f2bf(XA[3].x * rs + nm); o[5] = f2bf(XA[3].y * rs + nm);
    o[6] = f2bf(XA[3].z * rs + nm); o[7] = f2bf(XA[3].w * rs + nm);
    *(u16x8*)(ab + (amrow + 32) * 128 + awz) = o;
  };
  auto stageB = [&](int t) {
    char* bb = smem + (t & 1) * 40960 + 8192;
    const char* pb = gB + (size_t)t * 128;
#pragma unroll
    for (int i = 0; i < 8; ++i)
      gload16(pb + (size_t)i * 32 * KDIM * 2, bb + (i * 32 + w * 8) * 128);
  };
  auto mm = [&](int t) {
    const char* Ab = smem + (t & 1) * 40960;
    const char* Bb = Ab + 8192;
#pragma unroll
    for (int kk = 0; kk < 2; ++kk) {
      const int co = cs0 ^ (kk * 64);
      bf16x8 av[4], bv[4];
#pragma unroll
      for (int m = 0; m < 4; ++m)
        av[m] = *(const bf16x8*)(Ab + (m * 16 + l15) * 128 + co);
#pragma unroll
      for (int n = 0; n < 4; ++n)
        bv[n] = *(const bf16x8*)(Bb + (w * 64 + n * 16 + l15) * 128 + co);
#pragma unroll
      for (int m = 0; m < 4; ++m)
#pragma unroll
        for (int n = 0; n < 4; ++n)
          acc[m][n] = __builtin_amdgcn_mfma_f32_16x16x32_bf16(av[m], bv[n], acc[m][n], 0, 0, 0);
    }
  };

  // prologue: stage t=0 fully; prefetch regs for t=1
  loadx(xa0, st0, 0);
  writeA(xa0, st0, 0);
  stageB(0);
  loadx(xa1, st1, 1);
  __syncthreads();

  for (int t = 0; t < NT; t += 2) {
    // even step: compute buf0; prepare t+1 (buf1); prefetch regs t+2
    if (t + 1 < NT) { stageB(t + 1); writeA(xa1, st1, t + 1); }
    if (t + 2 < NT) loadx(xa0, st0, t + 2);
    mm(t);
    __syncthreads();
    // odd step: compute buf1; prepare t+2 (buf0); prefetch regs t+3
    if (t + 2 < NT) { stageB(t + 2); writeA(xa0, st0, t + 2); }
    if (t + 3 < NT) loadx(xa1, st1, t + 3);
    mm(t + 1);
    __syncthreads();
  }

  // epilogue: bias + fast gelu, f32 store
  // C/D layout (verified m89): col = l&15, row = (l>>4)*4 + reg
#pragma unroll
  for (int n = 0; n < 4; ++n) {
    const int col = ncol0 + w * 64 + n * 16 + l15;
    const float bb = biasf[col];
#pragma unroll
    for (int m = 0; m < 4; ++m) {
      const size_t rbase = mrow0 + m * 16 + lhi * 4;
#pragma unroll
      for (int r = 0; r < 4; ++r) {
        const float v = acc[m][n][r] + bb;
        out[(rbase + r) * NDIM + col] = gelu_f(v);
      }
    }
  }
}

// ---------------------------------------------------------------------------
extern "C" void kernel_launch(void* const* d_in, const int* in_sizes, int n_in,
                              void* d_out, int out_size, void* d_ws, size_t ws_size,
                              hipStream_t stream) {
  const float* x     = (const float*)d_in[0];
  const float* gamma = (const float*)d_in[1];
  const float* beta  = (const float*)d_in[2];
  const float* W     = (const float*)d_in[3];
  const float* b     = (const float*)d_in[4];
  float* out = (float*)d_out;

  // ws layout: WT 2MB | stats 512KB | partial 64KB | biasf 2KB
  char* p = (char*)d_ws;
  unsigned short* WT = (unsigned short*)p;            p += (size_t)NDIM * KDIM * 2;
  f32x2* stats       = (f32x2*)p;                     p += (size_t)XROWS * 8;
  float* partial     = (float*)p;                     p += (size_t)32 * NDIM * 4;
  float* biasf       = (float*)p;

  wt_kernel<<<256, 256, 0, stream>>>(W, gamma, WT);
  kbias1<<<32, 256, 0, stream>>>(W, beta, partial);
  kbias2<<<2, 256, 0, stream>>>(b, partial, biasf);
  stats_kernel<<<XROWS / 4, 256, 0, stream>>>(x, stats);
  gemm_kernel<<<(MROWS / 64) * 2, 256, 0, stream>>>(x, stats, WT, biasf, out);
}